// Round 1
// baseline (512.325 us; speedup 1.0000x reference)
//
#include <hip/hip_runtime.h>
#include <math.h>

// Problem constants (from reference)
#define KN   20000   // vocab
#define KH   40      // LSTM hidden
#define KDW  128     // W_down width
#define KND  16      // noise dim
#define KRW  8       // rw_len
#define KNS  512     // n_sample
#define KNCH 157     // ceil(KN / 128) wave-chunks of 128 cols
#define KEPS 1e-20f

__device__ __forceinline__ float sigmoidf_(float x) { return 1.0f / (1.0f + expf(-x)); }

// ---------------- init: 3-layer MLP (h0,c0) + LSTM step 0 (x=0) ----------------
__global__ void k_init(const float* __restrict__ z,
                       const float* __restrict__ l1w, const float* __restrict__ l1b,
                       const float* __restrict__ l2w, const float* __restrict__ l2b,
                       const float* __restrict__ l3w, const float* __restrict__ l3b,
                       const float* __restrict__ b_ih, const float* __restrict__ b_hh,
                       const float* __restrict__ w_hh,
                       float* __restrict__ h, float* __restrict__ c) {
  int s = blockIdx.x;
  int tid = threadIdx.x;
  __shared__ float zs[KND], inter[KH], h0[KH], c0[KH], g[4*KH];
  if (tid < KND) zs[tid] = z[s*KND + tid];
  __syncthreads();
  if (tid < KH) {
    float a = l1b[tid];
#pragma unroll
    for (int k = 0; k < KND; ++k) a = fmaf(zs[k], l1w[k*KH + tid], a);
    inter[tid] = tanhf(a);
  }
  __syncthreads();
  if (tid < KH) {
    float a2 = l2b[tid], a3 = l3b[tid];
#pragma unroll
    for (int k = 0; k < KH; ++k) {
      float iv = inter[k];
      a2 = fmaf(iv, l2w[k*KH + tid], a2);
      a3 = fmaf(iv, l3w[k*KH + tid], a3);
    }
    h0[tid] = tanhf(a2);
    c0[tid] = tanhf(a3);
  }
  __syncthreads();
  if (tid < 4*KH) {
    float a = b_ih[tid] + b_hh[tid];          // x0 = 0 -> no w_ih term
#pragma unroll 8
    for (int k = 0; k < KH; ++k) a = fmaf(h0[k], w_hh[k*4*KH + tid], a);
    g[tid] = a;
  }
  __syncthreads();
  if (tid < KH) {
    float gi = g[tid], gf = g[KH+tid], gg = g[2*KH+tid], go = g[3*KH+tid];
    float cn = sigmoidf_(gf) * c0[tid] + sigmoidf_(gi) * tanhf(gg);
    float hn = sigmoidf_(go) * tanhf(cn);
    h[s*KH + tid] = hn;
    c[s*KH + tid] = cn;
  }
}

// ------- per-step: reduce prev partial argmax -> idx, gather x=W_down[idx], LSTM cell -------
__global__ void k_step(const float* __restrict__ pval, const int* __restrict__ pidx,
                       int* __restrict__ idx_out,
                       const float* __restrict__ W_down,
                       const float* __restrict__ w_ih, const float* __restrict__ w_hh,
                       const float* __restrict__ b_ih, const float* __restrict__ b_hh,
                       float* __restrict__ h, float* __restrict__ c) {
  int s = blockIdx.x;
  int tid = threadIdx.x;
  __shared__ float sv[256];
  __shared__ int   si[256];
  __shared__ float xs[KDW], hs[KH], g[4*KH];
  float v = -INFINITY; int id = 0x7fffffff;
  if (tid < KNCH) { v = pval[s*KNCH + tid]; id = pidx[s*KNCH + tid]; }
  sv[tid] = v; si[tid] = id;
  __syncthreads();
  for (int off = 128; off > 0; off >>= 1) {
    if (tid < off) {
      float ov = sv[tid+off]; int oi = si[tid+off];
      if (ov > sv[tid] || (ov == sv[tid] && oi < si[tid])) { sv[tid] = ov; si[tid] = oi; }
    }
    __syncthreads();
  }
  int widx = si[0];
  if (tid == 0) idx_out[s] = widx;
  if (tid < KDW) xs[tid] = W_down[(size_t)widx*KDW + tid];
  if (tid >= KDW && tid < KDW + KH) hs[tid - KDW] = h[s*KH + (tid - KDW)];
  __syncthreads();
  if (tid < 4*KH) {
    float a = b_ih[tid] + b_hh[tid];
#pragma unroll 8
    for (int k = 0; k < KDW; ++k) a = fmaf(xs[k], w_ih[k*4*KH + tid], a);
#pragma unroll 8
    for (int k = 0; k < KH; ++k) a = fmaf(hs[k], w_hh[k*4*KH + tid], a);
    g[tid] = a;
  }
  __syncthreads();
  if (tid < KH) {
    float gi = g[tid], gf = g[KH+tid], gg2 = g[2*KH+tid], go = g[3*KH+tid];
    float cold = c[s*KH + tid];
    float cn = sigmoidf_(gf) * cold + sigmoidf_(gi) * tanhf(gg2);
    float hn = sigmoidf_(go) * tanhf(cn);
    h[s*KH + tid] = hn;
    c[s*KH + tid] = cn;
  }
}

// ------- big kernel: partial argmax over score = h.Wup_col + b_up + gumbel(u);
//         fused one-hot write of the PREVIOUS step's output -------
__global__ void __launch_bounds__(256) k_argmax(
    const float* __restrict__ u_t,          // gumbel_u + t*NS*N
    const float* __restrict__ h,            // [NS][KH]
    const float* __restrict__ W_up,         // [KH][KN]
    const float* __restrict__ b_up,         // [KN]
    float* __restrict__ pval, int* __restrict__ pidx,   // [NS][KNCH]
    const int* __restrict__ idx_prev,       // [NS] (valid iff write_prev)
    float* __restrict__ out_prev,           // out + (t-1)*KN (valid iff write_prev)
    int write_prev) {
  int ch   = blockIdx.x;          // 0..156, 128 cols each
  int sg   = blockIdx.y;          // 0..7, 64 samples each
  int tid  = threadIdx.x;
  int wave = tid >> 6, lane = tid & 63;
  int s0   = sg*64 + wave*16;     // 16 samples per wave
  int n0   = ch*128;

  // --- one-hot write of previous step (stores drain while we compute) ---
  if (write_prev) {
    int cw = n0 + 2*lane;
    if (cw < KN) {
      for (int ss = 0; ss < 16; ++ss) {
        int s = __builtin_amdgcn_readfirstlane(s0 + ss);
        int target = idx_prev[s];
        float2 v;
        v.x = (cw     == target) ? 1.0f : 0.0f;
        v.y = (cw + 1 == target) ? 1.0f : 0.0f;
        *reinterpret_cast<float2*>(out_prev + (size_t)s*(KRW*KN) + cw) = v;
      }
    }
  }

  // --- argmax over this chunk's 128 columns for 16 samples ---
  int cA = n0 + lane, cB = n0 + 64 + lane;
  bool vA = cA < KN, vB = cB < KN;
  int cAc = vA ? cA : 0, cBc = vB ? cB : 0;
  float wA[KH], wB[KH];
#pragma unroll
  for (int k = 0; k < KH; ++k) {
    wA[k] = W_up[k*KN + cAc];
    wB[k] = W_up[k*KN + cBc];
  }
  float bA = b_up[cAc], bB = b_up[cBc];

  for (int ss = 0; ss < 16; ++ss) {
    int s = __builtin_amdgcn_readfirstlane(s0 + ss);
    const float* __restrict__ ur = u_t + (size_t)s*KN;
    float uA = ur[cAc], uB = ur[cBc];
    float gA = -logf(-logf(uA + KEPS) + KEPS);
    float gB = -logf(-logf(uB + KEPS) + KEPS);
    const float* __restrict__ hr = h + s*KH;   // uniform -> scalar loads
    float scA = bA + gA, scB = bB + gB;
#pragma unroll
    for (int k = 0; k < KH; ++k) {
      float hk = hr[k];
      scA = fmaf(hk, wA[k], scA);
      scB = fmaf(hk, wB[k], scB);
    }
    if (!vA) scA = -INFINITY;
    if (!vB) scB = -INFINITY;
    float mv; int mi;
    if (scB > scA) { mv = scB; mi = cB; } else { mv = scA; mi = cA; }  // tie -> smaller idx
#pragma unroll
    for (int d = 32; d > 0; d >>= 1) {
      float ov = __shfl_xor(mv, d, 64);
      int   oi = __shfl_xor(mi, d, 64);
      if (ov > mv || (ov == mv && oi < mi)) { mv = ov; mi = oi; }      // first-index ties
    }
    if (lane == 0) { pval[s*KNCH + ch] = mv; pidx[s*KNCH + ch] = mi; }
  }
}

// ------- final reduce for step 7 -------
__global__ void k_reduce(const float* __restrict__ pval, const int* __restrict__ pidx,
                         int* __restrict__ idx_out) {
  int s = blockIdx.x;
  int tid = threadIdx.x;
  __shared__ float sv[256];
  __shared__ int   si[256];
  float v = -INFINITY; int id = 0x7fffffff;
  if (tid < KNCH) { v = pval[s*KNCH + tid]; id = pidx[s*KNCH + tid]; }
  sv[tid] = v; si[tid] = id;
  __syncthreads();
  for (int off = 128; off > 0; off >>= 1) {
    if (tid < off) {
      float ov = sv[tid+off]; int oi = si[tid+off];
      if (ov > sv[tid] || (ov == sv[tid] && oi < si[tid])) { sv[tid] = ov; si[tid] = oi; }
    }
    __syncthreads();
  }
  if (tid == 0) idx_out[s] = si[0];
}

// ------- one-hot write for step 7 -------
__global__ void k_write(const int* __restrict__ idx7, float* __restrict__ out_t) {
  int ch = blockIdx.x, sg = blockIdx.y, tid = threadIdx.x;
  int wave = tid >> 6, lane = tid & 63;
  int s0 = sg*64 + wave*16;
  int cw = ch*128 + 2*lane;
  if (cw >= KN) return;
  for (int ss = 0; ss < 16; ++ss) {
    int s = s0 + ss;
    int target = idx7[s];
    float2 v;
    v.x = (cw     == target) ? 1.0f : 0.0f;
    v.y = (cw + 1 == target) ? 1.0f : 0.0f;
    *reinterpret_cast<float2*>(out_t + (size_t)s*(KRW*KN) + cw) = v;
  }
}

extern "C" void kernel_launch(void* const* d_in, const int* in_sizes, int n_in,
                              void* d_out, int out_size, void* d_ws, size_t ws_size,
                              hipStream_t stream) {
  const float* z      = (const float*)d_in[0];
  const float* gu     = (const float*)d_in[1];
  const float* l1w    = (const float*)d_in[2];
  const float* l1b    = (const float*)d_in[3];
  const float* l2w    = (const float*)d_in[4];
  const float* l2b    = (const float*)d_in[5];
  const float* l3w    = (const float*)d_in[6];
  const float* l3b    = (const float*)d_in[7];
  const float* w_ih   = (const float*)d_in[8];
  const float* w_hh   = (const float*)d_in[9];
  const float* b_ih   = (const float*)d_in[10];
  const float* b_hh   = (const float*)d_in[11];
  const float* W_up   = (const float*)d_in[12];
  const float* b_up   = (const float*)d_in[13];
  const float* W_down = (const float*)d_in[14];
  float* out = (float*)d_out;

  // workspace layout (~824 KB)
  char* ws = (char*)d_ws;
  float* h    = (float*)(ws);                               // 512*40 f32
  float* c    = (float*)(ws + (size_t)KNS*KH*4);            // 512*40 f32
  float* pval = (float*)(ws + (size_t)2*KNS*KH*4);          // 512*157 f32
  int*   pidx = (int*)  (ws + (size_t)2*KNS*KH*4 + (size_t)KNS*KNCH*4);
  int*   idx  = (int*)  (ws + (size_t)2*KNS*KH*4 + (size_t)2*KNS*KNCH*4);  // 8*512 i32

  k_init<<<KNS, 256, 0, stream>>>(z, l1w, l1b, l2w, l2b, l3w, l3b, b_ih, b_hh, w_hh, h, c);

  for (int t = 0; t < KRW; ++t) {
    if (t > 0) {
      k_step<<<KNS, 256, 0, stream>>>(pval, pidx, idx + (t-1)*KNS, W_down,
                                      w_ih, w_hh, b_ih, b_hh, h, c);
    }
    k_argmax<<<dim3(KNCH, 8), 256, 0, stream>>>(
        gu + (size_t)t*KNS*KN, h, W_up, b_up, pval, pidx,
        idx + (t > 0 ? (t-1)*KNS : 0),
        out + (t > 0 ? (size_t)(t-1)*KN : 0),
        t > 0 ? 1 : 0);
  }
  k_reduce<<<KNS, 256, 0, stream>>>(pval, pidx, idx + 7*KNS);
  k_write<<<dim3(KNCH, 8), 256, 0, stream>>>(idx + 7*KNS, out + (size_t)7*KN);
}

// Round 2
// 344.895 us; speedup vs baseline: 1.4855x; 1.4855x over previous
//
#include <hip/hip_runtime.h>
#include <math.h>

// Problem constants (from reference)
#define KN   20000   // vocab
#define KH   40      // LSTM hidden
#define KDW  128     // W_down width
#define KND  16      // noise dim
#define KRW  8       // rw_len
#define KNS  512     // n_sample
#define KNCH 157     // ceil(KN / 128) wave-chunks of 128 cols
#define KEPS 1e-20f
#define KLN2 0.69314718055994531f

__device__ __forceinline__ float sigmoidf_(float x) { return 1.0f / (1.0f + expf(-x)); }

// pack (score, col) into a monotone-increasing u64 key; larger = better.
// ties on score -> smaller col wins (low field = ~col).
__device__ __forceinline__ unsigned long long packsc_(float v, int col) {
  unsigned u = __float_as_uint(v);
  unsigned key = (u >> 31) ? ~u : (u | 0x80000000u);
  return ((unsigned long long)key << 32) | (unsigned)(~col);
}

// ---------------- init: 3-layer MLP (h0,c0) + LSTM step 0 (x=0) ----------------
__global__ void k_init(const float* __restrict__ z,
                       const float* __restrict__ l1w, const float* __restrict__ l1b,
                       const float* __restrict__ l2w, const float* __restrict__ l2b,
                       const float* __restrict__ l3w, const float* __restrict__ l3b,
                       const float* __restrict__ b_ih, const float* __restrict__ b_hh,
                       const float* __restrict__ w_hh,
                       float* __restrict__ h, float* __restrict__ c) {
  int s = blockIdx.x;
  int tid = threadIdx.x;
  __shared__ float zs[KND], inter[KH], h0[KH], c0[KH], g[4*KH];
  if (tid < KND) zs[tid] = z[s*KND + tid];
  __syncthreads();
  if (tid < KH) {
    float a = l1b[tid];
#pragma unroll
    for (int k = 0; k < KND; ++k) a = fmaf(zs[k], l1w[k*KH + tid], a);
    inter[tid] = tanhf(a);
  }
  __syncthreads();
  if (tid < KH) {
    float a2 = l2b[tid], a3 = l3b[tid];
#pragma unroll
    for (int k = 0; k < KH; ++k) {
      float iv = inter[k];
      a2 = fmaf(iv, l2w[k*KH + tid], a2);
      a3 = fmaf(iv, l3w[k*KH + tid], a3);
    }
    h0[tid] = tanhf(a2);
    c0[tid] = tanhf(a3);
  }
  __syncthreads();
  if (tid < 4*KH) {
    float a = b_ih[tid] + b_hh[tid];          // x0 = 0 -> no w_ih term
#pragma unroll 8
    for (int k = 0; k < KH; ++k) a = fmaf(h0[k], w_hh[k*4*KH + tid], a);
    g[tid] = a;
  }
  __syncthreads();
  if (tid < KH) {
    float gi = g[tid], gf = g[KH+tid], gg = g[2*KH+tid], go = g[3*KH+tid];
    float cn = sigmoidf_(gf) * c0[tid] + sigmoidf_(gi) * tanhf(gg);
    float hn = sigmoidf_(go) * tanhf(cn);
    h[s*KH + tid] = hn;
    c[s*KH + tid] = cn;
  }
}

// ------- per-step: reduce prev partial argmax -> idx, gather x=W_down[idx], LSTM cell -------
__global__ void k_step(const unsigned long long* __restrict__ pp,
                       int* __restrict__ idx_out,
                       const float* __restrict__ W_down,
                       const float* __restrict__ w_ih, const float* __restrict__ w_hh,
                       const float* __restrict__ b_ih, const float* __restrict__ b_hh,
                       float* __restrict__ h, float* __restrict__ c) {
  int s = blockIdx.x;
  int tid = threadIdx.x;
  __shared__ unsigned long long sp[256];
  __shared__ float xs[KDW], hs[KH], g[4*KH];
  unsigned long long p = 0ull;
  if (tid < KNCH) p = pp[(size_t)s*KNCH + tid];
  sp[tid] = p;
  __syncthreads();
  for (int off = 128; off > 0; off >>= 1) {
    if (tid < off) {
      unsigned long long q = sp[tid+off];
      if (q > sp[tid]) sp[tid] = q;
    }
    __syncthreads();
  }
  int widx = (int)(~(unsigned)(sp[0] & 0xFFFFFFFFull));
  if (tid == 0) idx_out[s] = widx;
  if (tid < KDW) xs[tid] = W_down[(size_t)widx*KDW + tid];
  if (tid >= KDW && tid < KDW + KH) hs[tid - KDW] = h[s*KH + (tid - KDW)];
  __syncthreads();
  if (tid < 4*KH) {
    float a = b_ih[tid] + b_hh[tid];
#pragma unroll 8
    for (int k = 0; k < KDW; ++k) a = fmaf(xs[k], w_ih[k*4*KH + tid], a);
#pragma unroll 8
    for (int k = 0; k < KH; ++k) a = fmaf(hs[k], w_hh[k*4*KH + tid], a);
    g[tid] = a;
  }
  __syncthreads();
  if (tid < KH) {
    float gi = g[tid], gf = g[KH+tid], gg2 = g[2*KH+tid], go = g[3*KH+tid];
    float cold = c[s*KH + tid];
    float cn = sigmoidf_(gf) * cold + sigmoidf_(gi) * tanhf(gg2);
    float hn = sigmoidf_(go) * tanhf(cn);
    h[s*KH + tid] = hn;
    c[s*KH + tid] = cn;
  }
}

// ------- big kernel: partial argmax over score = h.Wup_col + b_up + gumbel(u);
//         fused one-hot write of the PREVIOUS step's output -------
// wave -> 8 samples x 128 cols; u loads software-pipelined; reduce batched at end.
__global__ void __launch_bounds__(256, 4) k_argmax(
    const float* __restrict__ u_t,          // gumbel_u + t*NS*N
    const float* __restrict__ h,            // [NS][KH]
    const float* __restrict__ W_up,         // [KH][KN]
    const float* __restrict__ b_up,         // [KN]
    unsigned long long* __restrict__ pp,    // [NS][KNCH] packed partials
    const int* __restrict__ idx_prev,       // [NS] (valid iff write_prev)
    float* __restrict__ out_prev,           // out + (t-1)*KN (valid iff write_prev)
    int write_prev) {
  int ch   = blockIdx.x;          // 0..156, 128 cols each
  int sg   = blockIdx.y;          // 0..15, 32 samples each
  int tid  = threadIdx.x;
  int wave = tid >> 6, lane = tid & 63;
  int s0   = __builtin_amdgcn_readfirstlane(sg*32 + wave*8);  // 8 samples per wave
  int n0   = ch*128;

  int cA = n0 + lane, cB = n0 + 64 + lane;
  bool vA = cA < KN, vB = cB < KN;
  int cAc = vA ? cA : 0, cBc = vB ? cB : 0;

  // prefetch first u row before anything else
  const float* up = u_t + (size_t)s0 * KN;
  float uA = up[cAc], uB = up[cBc];

  // W_up columns held in registers for all 8 samples
  float wA[KH], wB[KH];
#pragma unroll
  for (int k = 0; k < KH; ++k) {
    wA[k] = W_up[k*KN + cAc];
    wB[k] = W_up[k*KN + cBc];
  }
  float bA = b_up[cAc], bB = b_up[cBc];

  // --- one-hot write of previous step (stores drain while we compute) ---
  if (write_prev) {
    int tg[8];
#pragma unroll
    for (int ss = 0; ss < 8; ++ss) tg[ss] = idx_prev[s0 + ss];   // uniform -> s_load
    int cw = n0 + 2*lane;
    if (cw < KN) {
      float* op = out_prev + (size_t)s0 * (KRW*KN) + cw;
#pragma unroll
      for (int ss = 0; ss < 8; ++ss) {
        float2 v;
        v.x = (cw     == tg[ss]) ? 1.0f : 0.0f;
        v.y = (cw + 1 == tg[ss]) ? 1.0f : 0.0f;
        *reinterpret_cast<float2*>(op) = v;
        op += KRW*KN;
      }
    }
  }

  // --- main loop: 8 samples, u pipelined one iteration ahead ---
  unsigned long long p[8];
  const float* hr = h + s0*KH;                 // uniform -> scalar loads
#pragma unroll
  for (int ss = 0; ss < 8; ++ss) {
    float nA = 0.5f, nB = 0.5f;
    if (ss < 7) { nA = up[KN + cAc]; nB = up[KN + cBc]; }   // prefetch next sample's u
    float tA = fmaf(-KLN2, __log2f(uA + KEPS), KEPS);       // -ln(u+eps)+eps
    float tB = fmaf(-KLN2, __log2f(uB + KEPS), KEPS);
    float gA = -KLN2 * __log2f(tA);                          // -ln(.)
    float gB = -KLN2 * __log2f(tB);
    float scA = bA + gA, scB = bB + gB;
#pragma unroll
    for (int k = 0; k < KH; ++k) {
      float hk = hr[k];
      scA = fmaf(hk, wA[k], scA);
      scB = fmaf(hk, wB[k], scB);
    }
    unsigned long long pA = vA ? packsc_(scA, cA) : 0ull;
    unsigned long long pB = vB ? packsc_(scB, cB) : 0ull;
    p[ss] = (pB > pA) ? pB : pA;
    uA = nA; uB = nB;
    up += KN; hr += KH;
  }

  // --- batched cross-lane reduce: 8 independent 6-stage chains ---
#pragma unroll
  for (int d = 32; d > 0; d >>= 1) {
#pragma unroll
    for (int ss = 0; ss < 8; ++ss) {
      unsigned long long q = (unsigned long long)__shfl_xor((long long)p[ss], d, 64);
      if (q > p[ss]) p[ss] = q;
    }
  }
  if (lane == 0) {
#pragma unroll
    for (int ss = 0; ss < 8; ++ss) pp[(size_t)(s0+ss)*KNCH + ch] = p[ss];
  }
}

// ------- final reduce for step 7, fused with its one-hot write -------
__global__ void k_reduce_write(const unsigned long long* __restrict__ pp,
                               float* __restrict__ out) {
  int s = blockIdx.x;
  int tid = threadIdx.x;
  __shared__ unsigned long long sp[256];
  unsigned long long p = 0ull;
  if (tid < KNCH) p = pp[(size_t)s*KNCH + tid];
  sp[tid] = p;
  __syncthreads();
  for (int off = 128; off > 0; off >>= 1) {
    if (tid < off) {
      unsigned long long q = sp[tid+off];
      if (q > sp[tid]) sp[tid] = q;
    }
    __syncthreads();
  }
  int widx = (int)(~(unsigned)(sp[0] & 0xFFFFFFFFull));
  // write one-hot row for step 7: KN/4 = 5000 float4s across 256 threads
  float4* row = (float4*)(out + (size_t)s*(KRW*KN) + (size_t)7*KN);
  for (int j = tid; j < KN/4; j += 256) {
    float4 v = make_float4(0.f, 0.f, 0.f, 0.f);
    int base = j*4;
    if (widx - base >= 0 && widx - base < 4) {
      if (widx - base == 0) v.x = 1.f;
      else if (widx - base == 1) v.y = 1.f;
      else if (widx - base == 2) v.z = 1.f;
      else v.w = 1.f;
    }
    row[j] = v;
  }
}

extern "C" void kernel_launch(void* const* d_in, const int* in_sizes, int n_in,
                              void* d_out, int out_size, void* d_ws, size_t ws_size,
                              hipStream_t stream) {
  const float* z      = (const float*)d_in[0];
  const float* gu     = (const float*)d_in[1];
  const float* l1w    = (const float*)d_in[2];
  const float* l1b    = (const float*)d_in[3];
  const float* l2w    = (const float*)d_in[4];
  const float* l2b    = (const float*)d_in[5];
  const float* l3w    = (const float*)d_in[6];
  const float* l3b    = (const float*)d_in[7];
  const float* w_ih   = (const float*)d_in[8];
  const float* w_hh   = (const float*)d_in[9];
  const float* b_ih   = (const float*)d_in[10];
  const float* b_hh   = (const float*)d_in[11];
  const float* W_up   = (const float*)d_in[12];
  const float* b_up   = (const float*)d_in[13];
  const float* W_down = (const float*)d_in[14];
  float* out = (float*)d_out;

  // workspace layout (823296 B)
  char* ws = (char*)d_ws;
  float* h  = (float*)(ws);                                    // 512*40 f32
  float* c  = (float*)(ws + (size_t)KNS*KH*4);                 // 512*40 f32
  unsigned long long* pp = (unsigned long long*)(ws + (size_t)2*KNS*KH*4);  // 512*157 u64
  int* idx  = (int*)(ws + (size_t)2*KNS*KH*4 + (size_t)KNS*KNCH*8);         // 8*512 i32

  k_init<<<KNS, 256, 0, stream>>>(z, l1w, l1b, l2w, l2b, l3w, l3b, b_ih, b_hh, w_hh, h, c);

  for (int t = 0; t < KRW; ++t) {
    if (t > 0) {
      k_step<<<KNS, 256, 0, stream>>>(pp, idx + (t-1)*KNS, W_down,
                                      w_ih, w_hh, b_ih, b_hh, h, c);
    }
    k_argmax<<<dim3(KNCH, 16), 256, 0, stream>>>(
        gu + (size_t)t*KNS*KN, h, W_up, b_up, pp,
        idx + (t > 0 ? (t-1)*KNS : 0),
        out + (t > 0 ? (size_t)(t-1)*KN : 0),
        t > 0 ? 1 : 0);
  }
  k_reduce_write<<<KNS, 256, 0, stream>>>(pp, out);
}